// Round 12
// baseline (486.577 us; speedup 1.0000x reference)
//
#include <hip/hip_runtime.h>
#include <hip/hip_cooperative_groups.h>

namespace cg = cooperative_groups;

#define N_NODES 98304
#define N_EDGES 1572864
#define HIDDEN  64

#define NB      384      // buckets of 256 nodes; bucket = dst >> 8
#define NBLK    1536     // chunks; CHUNK*NBLK == N_EDGES; also the coop grid
#define CHUNK   1024     // edges per chunk (private payload region per block)
#define TPB     256
#define EPT     4        // 256*4 = 1024
#define SEG     4        // accumulation siblings per bucket
#define CPS     (NBLK / SEG)   // chunks per sibling = 384
#define NBX     (NB / 8)       // buckets per XCD = 48

#define FP_SCALE 1048576.0f          // 2^20
#define FP_INV   (1.0f / 1048576.0f)

__device__ __forceinline__ float silu_f(float x) {
    return x / (1.0f + __expf(-x));
}

// ---- phase 1: chunk sort (private region, linear write, no device atomics) ----
// payload u64: [63:37]=dr(27b) [36:10]=di(27b) [9:2]=local node(8b) [1]=inter flag
__device__ __forceinline__ void phase_scatter(const int* __restrict__ ei,
    const float* __restrict__ ew, const float* __restrict__ xr,
    const float* __restrict__ xi, const int* __restrict__ comm,
    unsigned short* __restrict__ lbT, unsigned long long* __restrict__ payload,
    int blk, int tid)
{
    __shared__ unsigned long long sorted[CHUNK];   // 8 KB
    __shared__ unsigned hist[NB];                  // 1.5 KB
    __shared__ unsigned localbase[NB];             // 1.5 KB

    for (int i = tid; i < NB; i += TPB) hist[i] = 0;
    __syncthreads();

    const int ebase = blk * CHUNK;
    unsigned long long pay[EPT];
    unsigned pb[EPT], pr[EPT];
#pragma unroll
    for (int k = 0; k < EPT; ++k) {
        const int e = ebase + k * TPB + tid;
        const int s = ei[e];
        const int d = ei[N_EDGES + e];
        const float w = ew[e];
        const int dr = __float2int_rn(w * xr[s] * FP_SCALE);
        const int di = __float2int_rn(w * xi[s] * FP_SCALE);
        const unsigned flag = (comm[s] == comm[d]) ? 0u : 1u;
        const unsigned b = (unsigned)d >> 8;
        pb[k] = b;
        pr[k] = atomicAdd(&hist[b], 1u);
        pay[k] = ((unsigned long long)((unsigned)dr & 0x07FFFFFFu) << 37)
               | ((unsigned long long)((unsigned)di & 0x07FFFFFFu) << 10)
               | ((unsigned)(d & 255) << 2) | ((unsigned long long)flag << 1);
    }
    __syncthreads();

    if (tid < 64) {   // wave 0: exclusive scan of hist -> localbase
        unsigned v[6];
        unsigned s = 0;
#pragma unroll
        for (int m = 0; m < 6; ++m) { v[m] = hist[tid * 6 + m]; s += v[m]; }
        unsigned p = s;
#pragma unroll
        for (int off = 1; off < 64; off <<= 1) {
            unsigned t = __shfl_up(p, off);
            if (tid >= off) p += t;
        }
        unsigned excl = p - s;
#pragma unroll
        for (int m = 0; m < 6; ++m) { unsigned t = v[m]; localbase[tid * 6 + m] = excl; excl += t; }
    }
    __syncthreads();

#pragma unroll
    for (int k = 0; k < EPT; ++k)
        sorted[localbase[pb[k]] + pr[k]] = pay[k];
    for (int i = tid; i < NB; i += TPB)
        lbT[(size_t)blk * NB + i] = (unsigned short)localbase[i];
    __syncthreads();

    for (int i = tid; i < CHUNK; i += TPB)
        payload[(size_t)blk * CHUNK + i] = sorted[i];
}

// ---- phase 2: run-gather accumulate, XCD-aware bucket grouping ----
// xcd = blk&7 (physical round-robin); buckets [48*xcd, 48*xcd+48) handled
// entirely by one XCD -> each payload/lbT line fetched by ~1 XCD, not ~3.
__device__ __forceinline__ void phase_accum(const unsigned long long* __restrict__ payload,
    const unsigned short* __restrict__ lbT, int* __restrict__ partial,
    int blk, int tid)
{
    __shared__ int accR[512];
    __shared__ int accI[512];
    const int xcd = blk & 7;
    const int j   = blk >> 3;              // 0..191
    const int bucket = xcd * NBX + (j >> 2);
    const int seg    = j & 3;
    accR[tid] = 0; accR[tid + 256] = 0;
    accI[tid] = 0; accI[tid + 256] = 0;
    __syncthreads();

    const int c0 = seg * CPS;
    for (int cc = tid; cc < CPS; cc += TPB) {
        const int c = c0 + cc;
        const unsigned base = lbT[(size_t)c * NB + bucket];
        const unsigned next = (bucket < NB - 1)
                            ? (unsigned)lbT[(size_t)c * NB + bucket + 1]
                            : (unsigned)CHUNK;
        const unsigned long long* chunkp = payload + (size_t)c * CHUNK;
        for (unsigned i = base; i < next; ++i) {
            const unsigned long long p = chunkp[i];
            const int dr = (int)((long long)p >> 37);
            const int di = (int)(((long long)(p << 27)) >> 37);
            const unsigned idx = (((unsigned)(p >> 2) & 255u) << 1) | ((unsigned)(p >> 1) & 1u);
            atomicAdd(&accR[idx], dr);
            atomicAdd(&accI[idx], di);
        }
    }
    __syncthreads();

    int* base = partial + ((size_t)(bucket * SEG + seg) << 10);
    base[tid]       = accR[tid];
    base[tid + 256] = accR[tid + 256];
    base[tid + 512] = accI[tid];
    base[tid + 768] = accI[tid + 256];
}

// ---- phase 3: sum 4 partials, decode, complex-mul + SiLU, 32 KB tile ----
__device__ __forceinline__ void phase_final(const int* __restrict__ partial,
    const float* __restrict__ Wlr, const float* __restrict__ Wli,
    const float* __restrict__ Wgr, const float* __restrict__ Wgi,
    float4* __restrict__ out, int blk, int tid)
{
    __shared__ float sR[128], sI[128];   // [ln*2 + sel], ln in [0,64)
    __shared__ float2 w_s[4][32];
    const int bucket = blk >> 2, q = blk & 3;

    if (tid < 128) {
        const int aidx = q * 128 + tid;   // (q*64+ln)*2+sel
        int sumR = 0, sumI = 0;
#pragma unroll
        for (int seg = 0; seg < SEG; ++seg) {
            const int* reg = partial + ((size_t)(bucket * SEG + seg) << 10);
            sumR += reg[aidx];
            sumI += reg[512 + aidx];
        }
        sR[tid] = (float)sumR * FP_INV;
        sI[tid] = (float)sumI * FP_INV;
    } else {
        const int t = tid - 128;
        const int which = t >> 5, h2 = t & 31;
        const float* W = (which == 0) ? Wlr : (which == 1) ? Wli
                       : (which == 2) ? Wgr : Wgi;
        w_s[which][h2] = ((const float2*)W)[h2];
    }
    __syncthreads();

#pragma unroll
    for (int j = 0; j < 8; ++j) {
        const int idx = j * 256 + tid;    // [0,2048): ln = idx>>5, h2 = idx&31
        const int ln  = idx >> 5;
        const int h2  = idx & 31;
        const float sr_l = sR[ln * 2 + 0], si_l = sI[ln * 2 + 0];
        const float sr_g = sR[ln * 2 + 1], si_g = sI[ln * 2 + 1];
        const float2 a = w_s[0][h2], c = w_s[1][h2];
        const float2 g = w_s[2][h2], f = w_s[3][h2];
        float4 o;
        {
            const float arl = a.x * sr_l - c.x * si_l;
            const float ail = c.x * sr_l + a.x * si_l;
            const float arg = g.x * sr_g - f.x * si_g;
            const float aig = f.x * sr_g + g.x * si_g;
            o.x = silu_f(arl) + silu_f(arg);
            o.y = silu_f(ail) + silu_f(aig);
        }
        {
            const float arl = a.y * sr_l - c.y * si_l;
            const float ail = c.y * sr_l + a.y * si_l;
            const float arg = g.y * sr_g - f.y * si_g;
            const float aig = f.y * sr_g + g.y * si_g;
            o.z = silu_f(arl) + silu_f(arg);
            o.w = silu_f(ail) + silu_f(aig);
        }
        out[(size_t)blk * 2048 + idx] = o;   // node n = blk*64+ln, elem = n*32+h2
    }
}

// ---- fused cooperative kernel: 1536 blocks co-resident, 2 grid syncs ----
__global__ __launch_bounds__(TPB, 6) void fused_coop_kernel(
    const int* ei, const float* ew, const float* xr, const float* xi,
    const int* comm, const float* Wlr, const float* Wli, const float* Wgr,
    const float* Wgi, unsigned short* lbT, unsigned long long* payload,
    int* partial, float4* out)
{
    const int tid = threadIdx.x, blk = blockIdx.x;
    phase_scatter(ei, ew, xr, xi, comm, lbT, payload, blk, tid);
    cg::this_grid().sync();
    phase_accum(payload, lbT, partial, blk, tid);
    cg::this_grid().sync();
    phase_final(partial, Wlr, Wli, Wgr, Wgi, out, blk, tid);
}

// ---- standalone wrappers (fallback if coop launch unavailable) ----
__global__ __launch_bounds__(TPB) void k_scatter(const int* ei, const float* ew,
    const float* xr, const float* xi, const int* comm,
    unsigned short* lbT, unsigned long long* payload)
{
    phase_scatter(ei, ew, xr, xi, comm, lbT, payload, blockIdx.x, threadIdx.x);
}
__global__ __launch_bounds__(TPB) void k_accum(const unsigned long long* payload,
    const unsigned short* lbT, int* partial)
{
    phase_accum(payload, lbT, partial, blockIdx.x, threadIdx.x);
}
__global__ __launch_bounds__(TPB) void k_final(const int* partial,
    const float* Wlr, const float* Wli, const float* Wgr, const float* Wgi,
    float4* out)
{
    phase_final(partial, Wlr, Wli, Wgr, Wgi, out, blockIdx.x, threadIdx.x);
}

// ---------------- minimal fallback (ws too small; never expected) ----------------
__global__ void edge_scatter_fb(const int* __restrict__ ei,
                                const float* __restrict__ ew,
                                const int* __restrict__ comm,
                                const float* __restrict__ xr,
                                const float* __restrict__ xi,
                                unsigned long long* __restrict__ P)
{
    const int e = blockIdx.x * blockDim.x + threadIdx.x;
    if (e >= N_EDGES) return;
    const int s = ei[e];
    const int d = ei[N_EDGES + e];
    const float w = ew[e];
    const int dr = __float2int_rn(w * xr[s] * FP_SCALE);
    const int di = __float2int_rn(w * xi[s] * FP_SCALE);
    const unsigned long long delta =
        (unsigned long long)(((long long)dr << 32) + (long long)di);
    const int base = (comm[s] == comm[d]) ? 0 : N_NODES;
    atomicAdd(&P[base + d], delta);
}

__global__ void epilogue_fb(const unsigned long long* __restrict__ P,
                            const float* __restrict__ Wlr,
                            const float* __restrict__ Wli,
                            const float* __restrict__ Wgr,
                            const float* __restrict__ Wgi,
                            float4* __restrict__ out)
{
    const int total = N_NODES * (HIDDEN / 2);
    const int t = blockIdx.x * blockDim.x + threadIdx.x;
    if (t >= total) return;
    const int n = t >> 5, h2 = t & 31;
    float sr_l, si_l, sr_g, si_g;
    {
        const unsigned long long U = P[n];
        const int bi = (int)(unsigned)(U & 0xffffffffULL);
        const int ar = (int)(unsigned)(U >> 32) + (bi < 0 ? 1 : 0);
        sr_l = (float)ar * FP_INV; si_l = (float)bi * FP_INV;
    }
    {
        const unsigned long long U = P[N_NODES + n];
        const int bi = (int)(unsigned)(U & 0xffffffffULL);
        const int ar = (int)(unsigned)(U >> 32) + (bi < 0 ? 1 : 0);
        sr_g = (float)ar * FP_INV; si_g = (float)bi * FP_INV;
    }
    const float2 wlr = ((const float2*)Wlr)[h2];
    const float2 wli = ((const float2*)Wli)[h2];
    const float2 wgr = ((const float2*)Wgr)[h2];
    const float2 wgi = ((const float2*)Wgi)[h2];
    float4 o;
    {
        const float arl = wlr.x * sr_l - wli.x * si_l;
        const float ail = wli.x * sr_l + wlr.x * si_l;
        const float arg = wgr.x * sr_g - wgi.x * si_g;
        const float aig = wgi.x * sr_g + wgr.x * si_g;
        o.x = silu_f(arl) + silu_f(arg);
        o.y = silu_f(ail) + silu_f(aig);
    }
    {
        const float arl = wlr.y * sr_l - wli.y * si_l;
        const float ail = wli.y * sr_l + wlr.y * si_l;
        const float arg = wgr.y * sr_g - wgi.y * si_g;
        const float aig = wgi.y * sr_g + wgr.y * si_g;
        o.z = silu_f(arl) + silu_f(arg);
        o.w = silu_f(ail) + silu_f(aig);
    }
    out[t] = o;
}

extern "C" void kernel_launch(void* const* d_in, const int* in_sizes, int n_in,
                              void* d_out, int out_size, void* d_ws, size_t ws_size,
                              hipStream_t stream) {
    const float* xr   = (const float*)d_in[0];
    const float* xi   = (const float*)d_in[1];
    const int*   ei   = (const int*)d_in[2];
    const float* ew   = (const float*)d_in[3];
    const int*   comm = (const int*)d_in[4];
    const float* Wlr  = (const float*)d_in[5];
    const float* Wli  = (const float*)d_in[6];
    const float* Wgr  = (const float*)d_in[7];
    const float* Wgi  = (const float*)d_in[8];

    const size_t payload_bytes = (size_t)N_EDGES * sizeof(unsigned long long);   // 12.58 MB
    const size_t lbT_bytes     = (size_t)NBLK * NB * sizeof(unsigned short);     // 1.18 MB
    const size_t partial_bytes = (size_t)NB * SEG * 1024 * sizeof(int);          // 6.29 MB
    const size_t need = payload_bytes + lbT_bytes + partial_bytes;               // ~20.1 MB

    if (ws_size >= need) {
        char* p = (char*)d_ws;
        unsigned long long* payload = (unsigned long long*)p;  p += payload_bytes;
        unsigned short* lbT         = (unsigned short*)p;      p += lbT_bytes;
        int* partial                = (int*)p;
        float4* outp                = (float4*)d_out;

        void* args[] = { (void*)&ei, (void*)&ew, (void*)&xr, (void*)&xi,
                         (void*)&comm, (void*)&Wlr, (void*)&Wli, (void*)&Wgr,
                         (void*)&Wgi, (void*)&lbT, (void*)&payload,
                         (void*)&partial, (void*)&outp };
        hipError_t err = hipLaunchCooperativeKernel((const void*)fused_coop_kernel,
                                                    dim3(NBLK), dim3(TPB),
                                                    args, 0, stream);
        if (err != hipSuccess) {
            // fallback: same phases as 3 ordinary kernels
            hipLaunchKernelGGL(k_scatter, dim3(NBLK), dim3(TPB), 0, stream,
                               ei, ew, xr, xi, comm, lbT, payload);
            hipLaunchKernelGGL(k_accum, dim3(NBLK), dim3(TPB), 0, stream,
                               payload, lbT, partial);
            hipLaunchKernelGGL(k_final, dim3(NBLK), dim3(TPB), 0, stream,
                               partial, Wlr, Wli, Wgr, Wgi, (float4*)d_out);
        }
    } else {
        unsigned long long* P = (unsigned long long*)d_ws;
        hipMemsetAsync(P, 0, (size_t)2 * N_NODES * sizeof(unsigned long long), stream);
        hipLaunchKernelGGL(edge_scatter_fb, dim3((N_EDGES + 255) / 256), dim3(256), 0, stream,
                           ei, ew, comm, xr, xi, P);
        const int total = N_NODES * (HIDDEN / 2);
        hipLaunchKernelGGL(epilogue_fb, dim3((total + 255) / 256), dim3(256), 0, stream,
                           P, Wlr, Wli, Wgr, Wgi, (float4*)d_out);
    }
}

// Round 14
// 91.737 us; speedup vs baseline: 5.3040x; 5.3040x over previous
//
#include <hip/hip_runtime.h>

#define N_NODES 98304
#define N_EDGES 1572864
#define HIDDEN  64

#define NB      384      // buckets of 256 nodes; bucket = dst >> 8
#define NBLK    1536     // chunks; CHUNK*NBLK == N_EDGES
#define CHUNK   1024     // edges per chunk (private payload region per block)
#define TPB     256
#define EPT     4        // 256*4 = 1024
#define NBX     (NB / 8) // buckets per XCD = 48

#define FP_SCALE 1048576.0f          // 2^20
#define FP_INV   (1.0f / 1048576.0f)

typedef float float4n __attribute__((ext_vector_type(4)));   // native vec for NT stores

__device__ __forceinline__ float silu_f(float x) {
    return x / (1.0f + __expf(-x));
}

// ---- kernel 1: private-chunk LDS counting sort ----
// payload u64: [63:37]=dr(27b) [36:10]=di(27b) [9:2]=local node(8b) [1]=inter flag
// Block sorts its 1024-edge chunk by bucket in LDS, writes it LINEARLY to its
// private payload region (fully coalesced, NO device atomics), and emits its
// per-bucket start offsets lbT[blk][b] (u16).
__global__ __launch_bounds__(TPB) void k_scatter(const int* __restrict__ ei,
    const float* __restrict__ ew, const float* __restrict__ xr,
    const float* __restrict__ xi, const int* __restrict__ comm,
    unsigned short* __restrict__ lbT, unsigned long long* __restrict__ payload)
{
    __shared__ unsigned long long sorted[CHUNK];   // 8 KB
    __shared__ unsigned hist[NB];                  // 1.5 KB
    __shared__ unsigned localbase[NB];             // 1.5 KB

    const int tid = threadIdx.x, blk = blockIdx.x;
    for (int i = tid; i < NB; i += TPB) hist[i] = 0;
    __syncthreads();

    const int ebase = blk * CHUNK;
    unsigned long long pay[EPT];
    unsigned pb[EPT], pr[EPT];
#pragma unroll
    for (int k = 0; k < EPT; ++k) {
        const int e = ebase + k * TPB + tid;
        const int s = __builtin_nontemporal_load(&ei[e]);
        const int d = __builtin_nontemporal_load(&ei[N_EDGES + e]);
        const float w = __builtin_nontemporal_load(&ew[e]);
        const int dr = __float2int_rn(w * xr[s] * FP_SCALE);
        const int di = __float2int_rn(w * xi[s] * FP_SCALE);
        const unsigned flag = (comm[s] == comm[d]) ? 0u : 1u;
        const unsigned b = (unsigned)d >> 8;
        pb[k] = b;
        pr[k] = atomicAdd(&hist[b], 1u);
        pay[k] = ((unsigned long long)((unsigned)dr & 0x07FFFFFFu) << 37)
               | ((unsigned long long)((unsigned)di & 0x07FFFFFFu) << 10)
               | ((unsigned)(d & 255) << 2) | ((unsigned long long)flag << 1);
    }
    __syncthreads();

    if (tid < 64) {   // wave 0: exclusive scan of hist -> localbase
        unsigned v[6];
        unsigned s = 0;
#pragma unroll
        for (int m = 0; m < 6; ++m) { v[m] = hist[tid * 6 + m]; s += v[m]; }
        unsigned p = s;
#pragma unroll
        for (int off = 1; off < 64; off <<= 1) {
            unsigned t = __shfl_up(p, off);
            if (tid >= off) p += t;
        }
        unsigned excl = p - s;
#pragma unroll
        for (int m = 0; m < 6; ++m) { unsigned t = v[m]; localbase[tid * 6 + m] = excl; excl += t; }
    }
    __syncthreads();

#pragma unroll
    for (int k = 0; k < EPT; ++k)
        sorted[localbase[pb[k]] + pr[k]] = pay[k];
    for (int i = tid; i < NB; i += TPB)
        lbT[(size_t)blk * NB + i] = (unsigned short)localbase[i];
    __syncthreads();

    // vectorized linear copyout (16 B per lane)
    const ulonglong2* src2 = (const ulonglong2*)sorted;
    ulonglong2* dst2 = (ulonglong2*)(payload + (size_t)blk * CHUNK);
#pragma unroll
    for (int i = tid; i < CHUNK / 2; i += TPB)
        dst2[i] = src2[i];
}

// ---- kernel 2: fused accumulate + epilogue ----
// 4 sibling blocks per bucket, all on ONE physical XCD (blk&7 round-robin):
// each scans the full bucket's runs across all 1536 chunks (payload lines
// land in the local L2 once; 3 of 4 sibling reads are L2 hits), accumulates
// its own 64-node range into i32 LDS, then epilogues a 32 KB output tile
// with nontemporal stores.
__global__ __launch_bounds__(TPB) void k_accum_final(
    const unsigned long long* __restrict__ payload,
    const unsigned short* __restrict__ lbT,
    const float* __restrict__ Wlr, const float* __restrict__ Wli,
    const float* __restrict__ Wgr, const float* __restrict__ Wgi,
    float* __restrict__ out)
{
    __shared__ int accR[128];   // [64 local nodes][intra/inter]
    __shared__ int accI[128];
    __shared__ float2 w_s[4][32];
    const int tid = threadIdx.x, blk = blockIdx.x;
    const int xcd = blk & 7;
    const int j   = blk >> 3;              // 0..191
    const int bucket = xcd * NBX + (j >> 2);
    const int seg    = j & 3;              // 64-node range within bucket

    if (tid < 128) { accR[tid] = 0; accI[tid] = 0; }
    else {
        const int t = tid - 128;
        const int which = t >> 5, h2 = t & 31;
        const float* W = (which == 0) ? Wlr : (which == 1) ? Wli
                       : (which == 2) ? Wgr : Wgi;
        w_s[which][h2] = ((const float2*)W)[h2];
    }
    __syncthreads();

    for (int c = tid; c < NBLK; c += TPB) {
        const unsigned base = lbT[(size_t)c * NB + bucket];
        const unsigned next = (bucket < NB - 1)
                            ? (unsigned)lbT[(size_t)c * NB + bucket + 1]
                            : (unsigned)CHUNK;
        const unsigned long long* chunkp = payload + (size_t)c * CHUNK;
        for (unsigned i = base; i < next; ++i) {
            const unsigned long long p = chunkp[i];
            const unsigned ln = (unsigned)(p >> 2) & 255u;
            if ((int)(ln >> 6) == seg) {
                const int dr = (int)((long long)p >> 37);
                const int di = (int)(((long long)(p << 27)) >> 37);
                const unsigned idx = ((ln & 63u) << 1) | ((unsigned)(p >> 1) & 1u);
                atomicAdd(&accR[idx], dr);
                atomicAdd(&accI[idx], di);
            }
        }
    }
    __syncthreads();

    float4n* outv = (float4n*)out;
    const size_t obase = (size_t)bucket * 8192 + (size_t)seg * 2048;
#pragma unroll
    for (int jj = 0; jj < 8; ++jj) {
        const int idx = jj * 256 + tid;   // 0..2047 = local node(0..63)*32 + h2
        const int ln  = idx >> 5;
        const int h2  = idx & 31;
        const float sr_l = (float)accR[ln * 2 + 0] * FP_INV;
        const float si_l = (float)accI[ln * 2 + 0] * FP_INV;
        const float sr_g = (float)accR[ln * 2 + 1] * FP_INV;
        const float si_g = (float)accI[ln * 2 + 1] * FP_INV;
        const float2 a = w_s[0][h2], c = w_s[1][h2];
        const float2 g = w_s[2][h2], f = w_s[3][h2];
        float4n o;
        {
            const float arl = a.x * sr_l - c.x * si_l;
            const float ail = c.x * sr_l + a.x * si_l;
            const float arg = g.x * sr_g - f.x * si_g;
            const float aig = f.x * sr_g + g.x * si_g;
            o.x = silu_f(arl) + silu_f(arg);
            o.y = silu_f(ail) + silu_f(aig);
        }
        {
            const float arl = a.y * sr_l - c.y * si_l;
            const float ail = c.y * sr_l + a.y * si_l;
            const float arg = g.y * sr_g - f.y * si_g;
            const float aig = f.y * sr_g + g.y * si_g;
            o.z = silu_f(arl) + silu_f(arg);
            o.w = silu_f(ail) + silu_f(aig);
        }
        __builtin_nontemporal_store(o, &outv[obase + idx]);
    }
}

// ---------------- minimal fallback (ws too small; never expected) ----------------
__global__ void edge_scatter_fb(const int* __restrict__ ei,
                                const float* __restrict__ ew,
                                const int* __restrict__ comm,
                                const float* __restrict__ xr,
                                const float* __restrict__ xi,
                                unsigned long long* __restrict__ P)
{
    const int e = blockIdx.x * blockDim.x + threadIdx.x;
    if (e >= N_EDGES) return;
    const int s = ei[e];
    const int d = ei[N_EDGES + e];
    const float w = ew[e];
    const int dr = __float2int_rn(w * xr[s] * FP_SCALE);
    const int di = __float2int_rn(w * xi[s] * FP_SCALE);
    const unsigned long long delta =
        (unsigned long long)(((long long)dr << 32) + (long long)di);
    const int base = (comm[s] == comm[d]) ? 0 : N_NODES;
    atomicAdd(&P[base + d], delta);
}

__global__ void epilogue_fb(const unsigned long long* __restrict__ P,
                            const float* __restrict__ Wlr,
                            const float* __restrict__ Wli,
                            const float* __restrict__ Wgr,
                            const float* __restrict__ Wgi,
                            float4* __restrict__ out)
{
    const int total = N_NODES * (HIDDEN / 2);
    const int t = blockIdx.x * blockDim.x + threadIdx.x;
    if (t >= total) return;
    const int n = t >> 5, h2 = t & 31;
    float sr_l, si_l, sr_g, si_g;
    {
        const unsigned long long U = P[n];
        const int bi = (int)(unsigned)(U & 0xffffffffULL);
        const int ar = (int)(unsigned)(U >> 32) + (bi < 0 ? 1 : 0);
        sr_l = (float)ar * FP_INV; si_l = (float)bi * FP_INV;
    }
    {
        const unsigned long long U = P[N_NODES + n];
        const int bi = (int)(unsigned)(U & 0xffffffffULL);
        const int ar = (int)(unsigned)(U >> 32) + (bi < 0 ? 1 : 0);
        sr_g = (float)ar * FP_INV; si_g = (float)bi * FP_INV;
    }
    const float2 wlr = ((const float2*)Wlr)[h2];
    const float2 wli = ((const float2*)Wli)[h2];
    const float2 wgr = ((const float2*)Wgr)[h2];
    const float2 wgi = ((const float2*)Wgi)[h2];
    float4 o;
    {
        const float arl = wlr.x * sr_l - wli.x * si_l;
        const float ail = wli.x * sr_l + wlr.x * si_l;
        const float arg = wgr.x * sr_g - wgi.x * si_g;
        const float aig = wgi.x * sr_g + wgr.x * si_g;
        o.x = silu_f(arl) + silu_f(arg);
        o.y = silu_f(ail) + silu_f(aig);
    }
    {
        const float arl = wlr.y * sr_l - wli.y * si_l;
        const float ail = wli.y * sr_l + wlr.y * si_l;
        const float arg = wgr.y * sr_g - wgi.y * si_g;
        const float aig = wgi.y * sr_g + wgr.y * si_g;
        o.z = silu_f(arl) + silu_f(arg);
        o.w = silu_f(ail) + silu_f(aig);
    }
    out[t] = o;
}

extern "C" void kernel_launch(void* const* d_in, const int* in_sizes, int n_in,
                              void* d_out, int out_size, void* d_ws, size_t ws_size,
                              hipStream_t stream) {
    const float* xr   = (const float*)d_in[0];
    const float* xi   = (const float*)d_in[1];
    const int*   ei   = (const int*)d_in[2];
    const float* ew   = (const float*)d_in[3];
    const int*   comm = (const int*)d_in[4];
    const float* Wlr  = (const float*)d_in[5];
    const float* Wli  = (const float*)d_in[6];
    const float* Wgr  = (const float*)d_in[7];
    const float* Wgi  = (const float*)d_in[8];

    const size_t payload_bytes = (size_t)N_EDGES * sizeof(unsigned long long);   // 12.58 MB
    const size_t lbT_bytes     = (size_t)NBLK * NB * sizeof(unsigned short);     // 1.18 MB
    const size_t need = payload_bytes + lbT_bytes;                               // ~13.8 MB

    if (ws_size >= need) {
        char* p = (char*)d_ws;
        unsigned long long* payload = (unsigned long long*)p;  p += payload_bytes;
        unsigned short* lbT         = (unsigned short*)p;

        hipLaunchKernelGGL(k_scatter, dim3(NBLK), dim3(TPB), 0, stream,
                           ei, ew, xr, xi, comm, lbT, payload);
        hipLaunchKernelGGL(k_accum_final, dim3(NBLK), dim3(TPB), 0, stream,
                           payload, lbT, Wlr, Wli, Wgr, Wgi, (float*)d_out);
    } else {
        unsigned long long* P = (unsigned long long*)d_ws;
        hipMemsetAsync(P, 0, (size_t)2 * N_NODES * sizeof(unsigned long long), stream);
        hipLaunchKernelGGL(edge_scatter_fb, dim3((N_EDGES + 255) / 256), dim3(256), 0, stream,
                           ei, ew, comm, xr, xi, P);
        const int total = N_NODES * (HIDDEN / 2);
        hipLaunchKernelGGL(epilogue_fb, dim3((total + 255) / 256), dim3(256), 0, stream,
                           P, Wlr, Wli, Wgr, Wgi, (float4*)d_out);
    }
}

// Round 15
// 64.723 us; speedup vs baseline: 7.5179x; 1.4174x over previous
//
#include <hip/hip_runtime.h>

#define N_NODES 98304
#define N_EDGES 1572864
#define HIDDEN  64

#define NB      1536     // buckets of 64 nodes; bucket = dst >> 6
#define NBLK    1536     // chunks; CHUNK*NBLK == N_EDGES
#define CHUNK   1024     // edges per chunk (private payload region per block)
#define TPB     256
#define EPT     4        // 256*4 = 1024
#define NBXC    (NB / 8) // buckets per XCD = 192

#define FP_SCALE 1048576.0f          // 2^20
#define FP_INV   (1.0f / 1048576.0f)

__device__ __forceinline__ float silu_f(float x) {
    return x / (1.0f + __expf(-x));
}

// ---- kernel 0: pack node table {xr, xi, comm} ----
__global__ __launch_bounds__(TPB) void prep_kernel(const float* __restrict__ xr,
                                                   const float* __restrict__ xi,
                                                   const int* __restrict__ comm,
                                                   float4* __restrict__ node)
{
    const int n = blockIdx.x * TPB + threadIdx.x;
    if (n < N_NODES) {
        float4 v;
        v.x = xr[n];
        v.y = xi[n];
        v.z = __int_as_float(comm[n]);
        v.w = 0.0f;
        node[n] = v;
    }
}

// ---- kernel 1: private-chunk LDS counting sort (fine buckets) ----
// payload u64: [63:37]=dr(27b) [36:10]=di(27b) [9:4]=local node(6b) [1]=inter flag
// Block sorts its 1024-edge chunk by bucket in LDS, writes it LINEARLY to its
// private payload region (fully coalesced, NO device atomics), and emits
// per-bucket start offsets lbT[blk][b] (u16).
__global__ __launch_bounds__(TPB) void k_scatter(const int* __restrict__ ei,
    const float* __restrict__ ew, const float4* __restrict__ node,
    const int* __restrict__ comm,
    unsigned short* __restrict__ lbT, unsigned long long* __restrict__ payload)
{
    __shared__ unsigned long long sorted[CHUNK];   // 8 KB
    __shared__ unsigned hist[NB];                  // 6 KB
    __shared__ unsigned localbase[NB];             // 6 KB

    const int tid = threadIdx.x, blk = blockIdx.x;
    for (int i = tid; i < NB; i += TPB) hist[i] = 0;
    __syncthreads();

    const int ebase = blk * CHUNK;
    unsigned long long pay[EPT];
    unsigned pb[EPT], pr[EPT];
#pragma unroll
    for (int k = 0; k < EPT; ++k) {
        const int e = ebase + k * TPB + tid;
        const int s = ei[e];
        const int d = ei[N_EDGES + e];
        const float w = ew[e];
        const float4 ns = node[s];
        const int cd = comm[d];
        const int dr = __float2int_rn(w * ns.x * FP_SCALE);
        const int di = __float2int_rn(w * ns.y * FP_SCALE);
        const unsigned flag = (__float_as_int(ns.z) == cd) ? 0u : 1u;
        const unsigned b = (unsigned)d >> 6;
        pb[k] = b;
        pr[k] = atomicAdd(&hist[b], 1u);
        pay[k] = ((unsigned long long)((unsigned)dr & 0x07FFFFFFu) << 37)
               | ((unsigned long long)((unsigned)di & 0x07FFFFFFu) << 10)
               | ((unsigned long long)((unsigned)(d & 63)) << 4)
               | ((unsigned long long)flag << 1);
    }
    __syncthreads();

    if (tid < 64) {   // wave 0: exclusive scan of 1536 counts, 24 per lane
        unsigned v[24];
        unsigned s = 0;
#pragma unroll
        for (int m = 0; m < 24; ++m) { v[m] = hist[tid * 24 + m]; s += v[m]; }
        unsigned p = s;
#pragma unroll
        for (int off = 1; off < 64; off <<= 1) {
            unsigned t = __shfl_up(p, off);
            if (tid >= off) p += t;
        }
        unsigned excl = p - s;
#pragma unroll
        for (int m = 0; m < 24; ++m) { unsigned t = v[m]; localbase[tid * 24 + m] = excl; excl += t; }
    }
    __syncthreads();

#pragma unroll
    for (int k = 0; k < EPT; ++k)
        sorted[localbase[pb[k]] + pr[k]] = pay[k];
    for (int i = tid; i < NB; i += TPB)
        lbT[(size_t)blk * NB + i] = (unsigned short)localbase[i];
    __syncthreads();

    // vectorized linear copyout (16 B per lane)
    const ulonglong2* src2 = (const ulonglong2*)sorted;
    ulonglong2* dst2 = (ulonglong2*)(payload + (size_t)blk * CHUNK);
#pragma unroll
    for (int i = tid; i < CHUNK / 2; i += TPB)
        dst2[i] = src2[i];
}

// ---- kernel 2: fused accumulate + epilogue, one block per 64-node bucket ----
// Each payload entry visited EXACTLY ONCE grid-wide. XCD swizzle groups
// adjacent buckets on one XCD so payload/lbT sectors (shared by neighbor
// buckets) are local-L2 hits.
__global__ __launch_bounds__(TPB) void k_accum_final(
    const unsigned long long* __restrict__ payload,
    const unsigned short* __restrict__ lbT,
    const float* __restrict__ Wlr, const float* __restrict__ Wli,
    const float* __restrict__ Wgr, const float* __restrict__ Wgi,
    float4* __restrict__ out)
{
    __shared__ int accR[128];   // [64 local nodes][intra/inter]
    __shared__ int accI[128];
    __shared__ float2 w_s[4][32];
    const int tid = threadIdx.x, blk = blockIdx.x;
    const int bucket = (blk & 7) * NBXC + (blk >> 3);   // adjacent buckets same XCD

    if (tid < 128) { accR[tid] = 0; accI[tid] = 0; }
    else {
        const int t = tid - 128;
        const int which = t >> 5, h2 = t & 31;
        const float* W = (which == 0) ? Wlr : (which == 1) ? Wli
                       : (which == 2) ? Wgr : Wgi;
        w_s[which][h2] = ((const float2*)W)[h2];
    }
    __syncthreads();

    // walk this bucket's run in every chunk (avg 0.67 entries/chunk)
    for (int c = tid; c < NBLK; c += TPB) {
        const unsigned start = lbT[(size_t)c * NB + bucket];
        const unsigned end   = (bucket < NB - 1)
                             ? (unsigned)lbT[(size_t)c * NB + bucket + 1]
                             : (unsigned)CHUNK;
        const unsigned long long* chunkp = payload + (size_t)c * CHUNK;
        for (unsigned i = start; i < end; ++i) {
            const unsigned long long p = chunkp[i];
            const int dr = (int)((long long)p >> 37);
            const int di = (int)(((long long)(p << 27)) >> 37);
            const unsigned idx = (((unsigned)(p >> 4) & 63u) << 1) | ((unsigned)(p >> 1) & 1u);
            atomicAdd(&accR[idx], dr);
            atomicAdd(&accI[idx], di);
        }
    }
    __syncthreads();

    const size_t obase = (size_t)bucket * 2048;
#pragma unroll
    for (int jj = 0; jj < 8; ++jj) {
        const int idx = jj * 256 + tid;   // 0..2047 = local node(0..63)*32 + h2
        const int ln  = idx >> 5;
        const int h2  = idx & 31;
        const float sr_l = (float)accR[ln * 2 + 0] * FP_INV;
        const float si_l = (float)accI[ln * 2 + 0] * FP_INV;
        const float sr_g = (float)accR[ln * 2 + 1] * FP_INV;
        const float si_g = (float)accI[ln * 2 + 1] * FP_INV;
        const float2 a = w_s[0][h2], c = w_s[1][h2];
        const float2 g = w_s[2][h2], f = w_s[3][h2];
        float4 o;
        {
            const float arl = a.x * sr_l - c.x * si_l;
            const float ail = c.x * sr_l + a.x * si_l;
            const float arg = g.x * sr_g - f.x * si_g;
            const float aig = f.x * sr_g + g.x * si_g;
            o.x = silu_f(arl) + silu_f(arg);
            o.y = silu_f(ail) + silu_f(aig);
        }
        {
            const float arl = a.y * sr_l - c.y * si_l;
            const float ail = c.y * sr_l + a.y * si_l;
            const float arg = g.y * sr_g - f.y * si_g;
            const float aig = f.y * sr_g + g.y * si_g;
            o.z = silu_f(arl) + silu_f(arg);
            o.w = silu_f(ail) + silu_f(aig);
        }
        out[obase + idx] = o;
    }
}

// ---------------- minimal fallback (ws too small; never expected) ----------------
__global__ void edge_scatter_fb(const int* __restrict__ ei,
                                const float* __restrict__ ew,
                                const int* __restrict__ comm,
                                const float* __restrict__ xr,
                                const float* __restrict__ xi,
                                unsigned long long* __restrict__ P)
{
    const int e = blockIdx.x * blockDim.x + threadIdx.x;
    if (e >= N_EDGES) return;
    const int s = ei[e];
    const int d = ei[N_EDGES + e];
    const float w = ew[e];
    const int dr = __float2int_rn(w * xr[s] * FP_SCALE);
    const int di = __float2int_rn(w * xi[s] * FP_SCALE);
    const unsigned long long delta =
        (unsigned long long)(((long long)dr << 32) + (long long)di);
    const int base = (comm[s] == comm[d]) ? 0 : N_NODES;
    atomicAdd(&P[base + d], delta);
}

__global__ void epilogue_fb(const unsigned long long* __restrict__ P,
                            const float* __restrict__ Wlr,
                            const float* __restrict__ Wli,
                            const float* __restrict__ Wgr,
                            const float* __restrict__ Wgi,
                            float4* __restrict__ out)
{
    const int total = N_NODES * (HIDDEN / 2);
    const int t = blockIdx.x * blockDim.x + threadIdx.x;
    if (t >= total) return;
    const int n = t >> 5, h2 = t & 31;
    float sr_l, si_l, sr_g, si_g;
    {
        const unsigned long long U = P[n];
        const int bi = (int)(unsigned)(U & 0xffffffffULL);
        const int ar = (int)(unsigned)(U >> 32) + (bi < 0 ? 1 : 0);
        sr_l = (float)ar * FP_INV; si_l = (float)bi * FP_INV;
    }
    {
        const unsigned long long U = P[N_NODES + n];
        const int bi = (int)(unsigned)(U & 0xffffffffULL);
        const int ar = (int)(unsigned)(U >> 32) + (bi < 0 ? 1 : 0);
        sr_g = (float)ar * FP_INV; si_g = (float)bi * FP_INV;
    }
    const float2 wlr = ((const float2*)Wlr)[h2];
    const float2 wli = ((const float2*)Wli)[h2];
    const float2 wgr = ((const float2*)Wgr)[h2];
    const float2 wgi = ((const float2*)Wgi)[h2];
    float4 o;
    {
        const float arl = wlr.x * sr_l - wli.x * si_l;
        const float ail = wli.x * sr_l + wlr.x * si_l;
        const float arg = wgr.x * sr_g - wgi.x * si_g;
        const float aig = wgi.x * sr_g + wgr.x * si_g;
        o.x = silu_f(arl) + silu_f(arg);
        o.y = silu_f(ail) + silu_f(aig);
    }
    {
        const float arl = wlr.y * sr_l - wli.y * si_l;
        const float ail = wli.y * sr_l + wlr.y * si_l;
        const float arg = wgr.y * sr_g - wgi.y * si_g;
        const float aig = wgi.y * sr_g + wgr.y * si_g;
        o.z = silu_f(arl) + silu_f(arg);
        o.w = silu_f(ail) + silu_f(aig);
    }
    out[t] = o;
}

extern "C" void kernel_launch(void* const* d_in, const int* in_sizes, int n_in,
                              void* d_out, int out_size, void* d_ws, size_t ws_size,
                              hipStream_t stream) {
    const float* xr   = (const float*)d_in[0];
    const float* xi   = (const float*)d_in[1];
    const int*   ei   = (const int*)d_in[2];
    const float* ew   = (const float*)d_in[3];
    const int*   comm = (const int*)d_in[4];
    const float* Wlr  = (const float*)d_in[5];
    const float* Wli  = (const float*)d_in[6];
    const float* Wgr  = (const float*)d_in[7];
    const float* Wgi  = (const float*)d_in[8];

    const size_t payload_bytes = (size_t)N_EDGES * sizeof(unsigned long long);   // 12.58 MB
    const size_t lbT_bytes     = (size_t)NBLK * NB * sizeof(unsigned short);     // 4.72 MB
    const size_t node_bytes    = (size_t)N_NODES * sizeof(float4);               // 1.57 MB
    const size_t need = payload_bytes + lbT_bytes + node_bytes;                  // ~18.9 MB

    if (ws_size >= need) {
        char* p = (char*)d_ws;
        unsigned long long* payload = (unsigned long long*)p;  p += payload_bytes;
        unsigned short* lbT         = (unsigned short*)p;      p += lbT_bytes;
        float4* node                = (float4*)p;

        hipLaunchKernelGGL(prep_kernel, dim3(N_NODES / TPB), dim3(TPB), 0, stream,
                           xr, xi, comm, node);
        hipLaunchKernelGGL(k_scatter, dim3(NBLK), dim3(TPB), 0, stream,
                           ei, ew, node, comm, lbT, payload);
        hipLaunchKernelGGL(k_accum_final, dim3(NB), dim3(TPB), 0, stream,
                           payload, lbT, Wlr, Wli, Wgr, Wgi, (float4*)d_out);
    } else {
        unsigned long long* P = (unsigned long long*)d_ws;
        hipMemsetAsync(P, 0, (size_t)2 * N_NODES * sizeof(unsigned long long), stream);
        hipLaunchKernelGGL(edge_scatter_fb, dim3((N_EDGES + 255) / 256), dim3(256), 0, stream,
                           ei, ew, comm, xr, xi, P);
        const int total = N_NODES * (HIDDEN / 2);
        hipLaunchKernelGGL(epilogue_fb, dim3((total + 255) / 256), dim3(256), 0, stream,
                           P, Wlr, Wli, Wgr, Wgi, (float4*)d_out);
    }
}